// Round 14
// baseline (199.695 us; speedup 1.0000x reference)
//
#include <hip/hip_runtime.h>
#include <hip/hip_bf16.h>

#define N_NODES 100000
#define N_EDGES 1600000
#define F_IN 128
#define HID 64
#define NC 10

#define BSH 7
#define BNODES 128                       // nodes per bucket = 1<<BSH
#define NB 782                           // ceil(100000/128)
#define CAP 2560                         // padded bucket capacity (λ=2048, +11σ)
#define PBLK 256                         // partition blocks
#define TILE ((N_EDGES + PBLK - 1) / PBLK)  // 6250 edges per block

#define XROWS 64
#define XPAD 132                         // 528 B row: 16B-aligned, 2-way banks (free)

__device__ __forceinline__ unsigned short f2bf(float f) {
    unsigned u = __float_as_uint(f);
    u += 0x7FFFu + ((u >> 16) & 1u);     // round-to-nearest-even
    return (unsigned short)(u >> 16);
}
__device__ __forceinline__ float bf2f(unsigned short b) {
    return __uint_as_float(((unsigned)b) << 16);
}

// ---------------- init: bcursor[b] = b*CAP
__global__ void k_init(int* __restrict__ bcursor) {
    int b = blockIdx.x * blockDim.x + threadIdx.x;
    if (b < NB) bcursor[b] = b * CAP;
}

// ---------------- s3: partition edges into padded bucket regions
// ppair entry = src | (local_dst << 20)
__global__ __launch_bounds__(256) void s3_part(const int* __restrict__ src,
                                               const int* __restrict__ dst,
                                               int* __restrict__ bcursor,
                                               unsigned* __restrict__ ppair) {
    __shared__ int lh[NB];     // histogram, then running cursor
    int t = threadIdx.x;
    for (int k = t; k < NB; k += 256) lh[k] = 0;
    __syncthreads();
    int b0 = blockIdx.x * TILE;
    int b1 = b0 + TILE < N_EDGES ? b0 + TILE : N_EDGES;
    for (int i = b0 + t; i < b1; i += 256)
        atomicAdd(&lh[dst[i] >> BSH], 1);
    __syncthreads();
    for (int k = t; k < NB; k += 256) {
        int c = lh[k];
        lh[k] = c ? atomicAdd(&bcursor[k], c) : 0;   // coalesced, with return
    }
    __syncthreads();
    for (int i = b0 + t; i < b1; i += 256) {
        int d = dst[i];
        int slot = atomicAdd(&lh[d >> BSH], 1);      // LDS atomic (fast)
        ppair[slot] = (unsigned)src[i] | ((unsigned)(d & (BNODES - 1)) << 20);
    }
}

// ---------------- s4: per-bucket CSR finalize (row_info, dis, padded csr)
__global__ __launch_bounds__(256) void s4_build(const unsigned* __restrict__ ppair,
                                                const int* __restrict__ bcursor,
                                                int2* __restrict__ row_info,
                                                float* __restrict__ dis,
                                                int* __restrict__ csr) {
    __shared__ int h[BNODES];
    __shared__ int sc[BNODES];
    __shared__ int lcur[BNODES];
    int t = threadIdx.x;
    int b = blockIdx.x;
    int base = b * CAP;
    int cnt = bcursor[b] - base;
    int nodes0 = b << BSH;
    if (t < BNODES) h[t] = 0;
    __syncthreads();
    for (int j = t; j < cnt; j += 256)
        atomicAdd(&h[ppair[base + j] >> 20], 1);
    __syncthreads();
    if (t < BNODES) sc[t] = h[t];
    __syncthreads();
    for (int off = 1; off < BNODES; off <<= 1) {
        int u = (t < BNODES && t >= off) ? sc[t - off] : 0;
        __syncthreads();
        if (t < BNODES) sc[t] += u;
        __syncthreads();
    }
    if (t < BNODES) {
        int node = nodes0 + t;
        int excl = sc[t] - h[t];
        if (node < N_NODES) {
            row_info[node] = make_int2(base + excl, h[t]);
            dis[node] = rsqrtf((float)(h[t] + 1));
            lcur[t] = base + excl;
        }
    }
    __syncthreads();
    for (int j = t; j < cnt; j += 256) {
        unsigned p = ppair[base + j];
        int slot = atomicAdd(&lcur[p >> 20], 1);        // LDS atomic
        csr[slot] = (int)(p & 0xFFFFFu);
    }
}

__device__ __forceinline__ float4 fma4(float s, float4 w, float4 a) {
    a.x = fmaf(s, w.x, a.x);
    a.y = fmaf(s, w.y, a.y);
    a.z = fmaf(s, w.z, a.z);
    a.w = fmaf(s, w.w, a.w);
    return a;
}

// ---------------- hxs = bf16((x @ W1) * dis) ; 64x64 LDS-tiled, 4x4 per thread
__global__ __launch_bounds__(256) void k_xw(const float* __restrict__ x,
                                            const float* __restrict__ W1,
                                            const float* __restrict__ dis,
                                            unsigned short* __restrict__ hxs) {
    __shared__ float Ws[F_IN * HID];      // 32 KB, [k][c] (== W1 layout)
    __shared__ float Xs[XROWS * XPAD];    // 33 KB, [n][k] padded
    int t = threadIdx.x;
    int base = blockIdx.x * XROWS;

    for (int i = t; i < (F_IN * HID) / 4; i += 256)
        reinterpret_cast<float4*>(Ws)[i] = reinterpret_cast<const float4*>(W1)[i];

    for (int i = t; i < XROWS * (F_IN / 4); i += 256) {
        int n = i >> 5;           // 32 float4 per row
        int kq = i & 31;
        int gn = base + n;
        float4 v = make_float4(0.f, 0.f, 0.f, 0.f);
        if (gn < N_NODES)
            v = reinterpret_cast<const float4*>(x + (size_t)gn * F_IN)[kq];
        *reinterpret_cast<float4*>(&Xs[n * XPAD + kq * 4]) = v;
    }
    __syncthreads();

    int cg = (t & 15) * 4;        // col base: 16 groups x 4 cols
    int ng = (t >> 4) * 4;        // node base: 16 groups x 4 nodes
    float4 a0 = make_float4(0.f, 0.f, 0.f, 0.f);
    float4 a1 = a0, a2 = a0, a3 = a0;

#pragma unroll 4
    for (int k0 = 0; k0 < F_IN; k0 += 4) {
        float4 w0 = *reinterpret_cast<const float4*>(&Ws[(k0 + 0) * HID + cg]);
        float4 w1 = *reinterpret_cast<const float4*>(&Ws[(k0 + 1) * HID + cg]);
        float4 w2 = *reinterpret_cast<const float4*>(&Ws[(k0 + 2) * HID + cg]);
        float4 w3 = *reinterpret_cast<const float4*>(&Ws[(k0 + 3) * HID + cg]);
        float4 x0 = *reinterpret_cast<const float4*>(&Xs[(ng + 0) * XPAD + k0]);
        float4 x1 = *reinterpret_cast<const float4*>(&Xs[(ng + 1) * XPAD + k0]);
        float4 x2 = *reinterpret_cast<const float4*>(&Xs[(ng + 2) * XPAD + k0]);
        float4 x3 = *reinterpret_cast<const float4*>(&Xs[(ng + 3) * XPAD + k0]);
        a0 = fma4(x0.x, w0, a0); a0 = fma4(x0.y, w1, a0);
        a0 = fma4(x0.z, w2, a0); a0 = fma4(x0.w, w3, a0);
        a1 = fma4(x1.x, w0, a1); a1 = fma4(x1.y, w1, a1);
        a1 = fma4(x1.z, w2, a1); a1 = fma4(x1.w, w3, a1);
        a2 = fma4(x2.x, w0, a2); a2 = fma4(x2.y, w1, a2);
        a2 = fma4(x2.z, w2, a2); a2 = fma4(x2.w, w3, a2);
        a3 = fma4(x3.x, w0, a3); a3 = fma4(x3.y, w1, a3);
        a3 = fma4(x3.z, w2, a3); a3 = fma4(x3.w, w3, a3);
    }

    int n0 = base + ng;
    if (n0 + 0 < N_NODES) {
        float d = dis[n0 + 0];
        ushort4 o; o.x = f2bf(a0.x * d); o.y = f2bf(a0.y * d);
        o.z = f2bf(a0.z * d); o.w = f2bf(a0.w * d);
        *reinterpret_cast<ushort4*>(&hxs[(size_t)(n0 + 0) * HID + cg]) = o;
    }
    if (n0 + 1 < N_NODES) {
        float d = dis[n0 + 1];
        ushort4 o; o.x = f2bf(a1.x * d); o.y = f2bf(a1.y * d);
        o.z = f2bf(a1.z * d); o.w = f2bf(a1.w * d);
        *reinterpret_cast<ushort4*>(&hxs[(size_t)(n0 + 1) * HID + cg]) = o;
    }
    if (n0 + 2 < N_NODES) {
        float d = dis[n0 + 2];
        ushort4 o; o.x = f2bf(a2.x * d); o.y = f2bf(a2.y * d);
        o.z = f2bf(a2.z * d); o.w = f2bf(a2.w * d);
        *reinterpret_cast<ushort4*>(&hxs[(size_t)(n0 + 2) * HID + cg]) = o;
    }
    if (n0 + 3 < N_NODES) {
        float d = dis[n0 + 3];
        ushort4 o; o.x = f2bf(a3.x * d); o.y = f2bf(a3.y * d);
        o.z = f2bf(a3.z * d); o.w = f2bf(a3.w * d);
        *reinterpret_cast<ushort4*>(&hxs[(size_t)(n0 + 3) * HID + cg]) = o;
    }
}

// ---------------- fused layer-1 aggregate + bias + relu + W2 + scale -> bf16 h2s
// One wave per node; lane&31 = uint col-pair; lane>>5 = edge parity.
// R14: W2/b1 staged in LDS (off the VMEM pipe); 32-bit saddr-form gather offsets.
__global__ __launch_bounds__(256) void k_agg1f(const int2* __restrict__ row_info,
                                               const float* __restrict__ dis,
                                               const unsigned* __restrict__ hxsu,
                                               const int* __restrict__ csr,
                                               const float* __restrict__ b1,
                                               const float* __restrict__ W2,
                                               unsigned short* __restrict__ h2s) {
    __shared__ float W2t[NC][HID];        // transposed [c][k], 2.5 KB
    __shared__ float b1s[HID];
    int t = threadIdx.x;
    for (int i = t; i < NC * HID; i += 256) {
        int k = i / NC, c = i - k * NC;   // W2 is [k][c] row-major
        W2t[c][k] = W2[i];
    }
    if (t < HID) b1s[t] = b1[t];
    __syncthreads();

    int lane = t & 63;
    int node = (int)((blockIdx.x * 256u + (unsigned)t) >> 6);
    if (node >= N_NODES) return;          // grid is exact; never triggers
    int col2 = lane & 31;
    int half = lane >> 5;

    int2 ri = row_info[node];
    int beg = ri.x, m = ri.y;
    float ax = 0.f, ay = 0.f;
    int mmain = m & ~15;
    int j = 0;
    for (; j < mmain; j += 16) {                  // 16 edges per iter, 8 per half
        int i0 = beg + j + half;
        int e0 = csr[i0],      e1 = csr[i0 + 2];
        int e2 = csr[i0 + 4],  e3 = csr[i0 + 6];
        int e4 = csr[i0 + 8],  e5 = csr[i0 + 10];
        int e6 = csr[i0 + 12], e7 = csr[i0 + 14];
        unsigned u0 = hxsu[((unsigned)e0 << 5) + (unsigned)col2];
        unsigned u1 = hxsu[((unsigned)e1 << 5) + (unsigned)col2];
        unsigned u2 = hxsu[((unsigned)e2 << 5) + (unsigned)col2];
        unsigned u3 = hxsu[((unsigned)e3 << 5) + (unsigned)col2];
        unsigned u4 = hxsu[((unsigned)e4 << 5) + (unsigned)col2];
        unsigned u5 = hxsu[((unsigned)e5 << 5) + (unsigned)col2];
        unsigned u6 = hxsu[((unsigned)e6 << 5) + (unsigned)col2];
        unsigned u7 = hxsu[((unsigned)e7 << 5) + (unsigned)col2];
        ax += __uint_as_float(u0 << 16); ay += __uint_as_float(u0 & 0xffff0000u);
        ax += __uint_as_float(u1 << 16); ay += __uint_as_float(u1 & 0xffff0000u);
        ax += __uint_as_float(u2 << 16); ay += __uint_as_float(u2 & 0xffff0000u);
        ax += __uint_as_float(u3 << 16); ay += __uint_as_float(u3 & 0xffff0000u);
        ax += __uint_as_float(u4 << 16); ay += __uint_as_float(u4 & 0xffff0000u);
        ax += __uint_as_float(u5 << 16); ay += __uint_as_float(u5 & 0xffff0000u);
        ax += __uint_as_float(u6 << 16); ay += __uint_as_float(u6 & 0xffff0000u);
        ax += __uint_as_float(u7 << 16); ay += __uint_as_float(u7 & 0xffff0000u);
    }
#pragma unroll 2
    for (int r = 0; r < 2; ++r) {
        if (j < m) {                              // predicated 8-edge round
            int i0 = j + half;
            bool v0 = i0 < m, v1 = i0 + 2 < m, v2 = i0 + 4 < m, v3 = i0 + 6 < m;
            int e0 = csr[beg + (v0 ? i0     : 0)];
            int e1 = csr[beg + (v1 ? i0 + 2 : 0)];
            int e2 = csr[beg + (v2 ? i0 + 4 : 0)];
            int e3 = csr[beg + (v3 ? i0 + 6 : 0)];
            unsigned u0 = hxsu[((unsigned)e0 << 5) + (unsigned)col2];
            unsigned u1 = hxsu[((unsigned)e1 << 5) + (unsigned)col2];
            unsigned u2 = hxsu[((unsigned)e2 << 5) + (unsigned)col2];
            unsigned u3 = hxsu[((unsigned)e3 << 5) + (unsigned)col2];
            ax += v0 ? __uint_as_float(u0 << 16) : 0.f;
            ay += v0 ? __uint_as_float(u0 & 0xffff0000u) : 0.f;
            ax += v1 ? __uint_as_float(u1 << 16) : 0.f;
            ay += v1 ? __uint_as_float(u1 & 0xffff0000u) : 0.f;
            ax += v2 ? __uint_as_float(u2 << 16) : 0.f;
            ay += v2 ? __uint_as_float(u2 & 0xffff0000u) : 0.f;
            ax += v3 ? __uint_as_float(u3 << 16) : 0.f;
            ay += v3 ? __uint_as_float(u3 & 0xffff0000u) : 0.f;
        }
        j += 8;
    }
    // merge edge-parity halves
    ax += __shfl_xor(ax, 32);
    ay += __shfl_xor(ay, 32);
    // self message
    unsigned us = hxsu[((unsigned)node << 5) + (unsigned)col2];
    ax += __uint_as_float(us << 16);
    ay += __uint_as_float(us & 0xffff0000u);

    float dn = dis[node];
    float vx = ax * dn + b1s[2 * col2];     vx = vx > 0.f ? vx : 0.f;
    float vy = ay * dn + b1s[2 * col2 + 1]; vy = vy > 0.f ? vy : 0.f;

    // W2 from LDS (2-way bank aliasing = free); 20 ds_read_b32 off the VMEM pipe
    float s0 = vx * W2t[0][2 * col2] + vy * W2t[0][2 * col2 + 1];
    float s1 = vx * W2t[1][2 * col2] + vy * W2t[1][2 * col2 + 1];
    float s2 = vx * W2t[2][2 * col2] + vy * W2t[2][2 * col2 + 1];
    float s3 = vx * W2t[3][2 * col2] + vy * W2t[3][2 * col2 + 1];
    float s4 = vx * W2t[4][2 * col2] + vy * W2t[4][2 * col2 + 1];
    float s5 = vx * W2t[5][2 * col2] + vy * W2t[5][2 * col2 + 1];
    float s6 = vx * W2t[6][2 * col2] + vy * W2t[6][2 * col2 + 1];
    float s7 = vx * W2t[7][2 * col2] + vy * W2t[7][2 * col2 + 1];
    float s8 = vx * W2t[8][2 * col2] + vy * W2t[8][2 * col2 + 1];
    float s9 = vx * W2t[9][2 * col2] + vy * W2t[9][2 * col2 + 1];
#pragma unroll
    for (int off = 16; off >= 1; off >>= 1) {     // 5 rounds over 32-lane halves
        s0 += __shfl_xor(s0, off); s1 += __shfl_xor(s1, off);
        s2 += __shfl_xor(s2, off); s3 += __shfl_xor(s3, off);
        s4 += __shfl_xor(s4, off); s5 += __shfl_xor(s5, off);
        s6 += __shfl_xor(s6, off); s7 += __shfl_xor(s7, off);
        s8 += __shfl_xor(s8, off); s9 += __shfl_xor(s9, off);
    }
    float o = s0;
    o = (lane == 1) ? s1 : o; o = (lane == 2) ? s2 : o;
    o = (lane == 3) ? s3 : o; o = (lane == 4) ? s4 : o;
    o = (lane == 5) ? s5 : o; o = (lane == 6) ? s6 : o;
    o = (lane == 7) ? s7 : o; o = (lane == 8) ? s8 : o;
    o = (lane == 9) ? s9 : o;
    if (lane < NC)
        h2s[(size_t)node * NC + lane] = f2bf(o * dn);
}

// ---------------- layer-2 aggregate + bias + log_softmax (bf16 h2s)
// 16 lanes per node; 4 edges per iter + predicated 4-edge tail. (R12 version)
__global__ __launch_bounds__(256) void k_agg2f(const int2* __restrict__ row_info,
                                               const float* __restrict__ dis,
                                               const unsigned short* __restrict__ h2s,
                                               const int* __restrict__ csr,
                                               const float* __restrict__ b2,
                                               float* __restrict__ out) {
    int c = threadIdx.x & 15;  // 16 lanes per node, 10 active
    int node = (blockIdx.x * blockDim.x + threadIdx.x) >> 4;
    if (node >= N_NODES) return;
    int cc = c < NC ? c : 0;
    int2 ri = row_info[node];
    int beg = ri.x, m = ri.y;
    float acc = bf2f(h2s[(size_t)node * NC + cc]);
    int mmain = m & ~3;
    int j = 0;
    for (; j < mmain; j += 4) {                   // 4 independent loads in flight
        int e0 = csr[beg + j],     e1 = csr[beg + j + 1];
        int e2 = csr[beg + j + 2], e3 = csr[beg + j + 3];
        float f0 = bf2f(h2s[(size_t)e0 * NC + cc]);
        float f1 = bf2f(h2s[(size_t)e1 * NC + cc]);
        float f2 = bf2f(h2s[(size_t)e2 * NC + cc]);
        float f3 = bf2f(h2s[(size_t)e3 * NC + cc]);
        acc += f0 + f1 + f2 + f3;
    }
    if (j < m) {                                  // predicated 4-edge tail
        bool v0 = j < m, v1 = j + 1 < m, v2 = j + 2 < m, v3 = j + 3 < m;
        int e0 = csr[beg + (v0 ? j     : 0)];
        int e1 = csr[beg + (v1 ? j + 1 : 0)];
        int e2 = csr[beg + (v2 ? j + 2 : 0)];
        int e3 = csr[beg + (v3 ? j + 3 : 0)];
        float f0 = bf2f(h2s[(size_t)e0 * NC + cc]);
        float f1 = bf2f(h2s[(size_t)e1 * NC + cc]);
        float f2 = bf2f(h2s[(size_t)e2 * NC + cc]);
        float f3 = bf2f(h2s[(size_t)e3 * NC + cc]);
        acc += v0 ? f0 : 0.f;
        acc += v1 ? f1 : 0.f;
        acc += v2 ? f2 : 0.f;
        acc += v3 ? f3 : 0.f;
    }
    acc = acc * dis[node] + b2[cc];
    float accm = (c < NC) ? acc : -1e30f;
    float mx = accm;
#pragma unroll
    for (int off = 8; off >= 1; off >>= 1)
        mx = fmaxf(mx, __shfl_xor(mx, off, 16));
    float e = (c < NC) ? expf(acc - mx) : 0.f;
    float ssum = e;
#pragma unroll
    for (int off = 8; off >= 1; off >>= 1)
        ssum += __shfl_xor(ssum, off, 16);
    float lse = mx + logf(ssum);
    if (c < NC) out[(size_t)node * NC + c] = acc - lse;
}

static inline size_t align16(size_t v) { return (v + 15) & ~(size_t)15; }

extern "C" void kernel_launch(void* const* d_in, const int* in_sizes, int n_in,
                              void* d_out, int out_size, void* d_ws, size_t ws_size,
                              hipStream_t stream) {
    const float* x  = (const float*)d_in[0];
    const int*   ei = (const int*)d_in[1];    // [2, E] int32 (JAX x64 off)
    const float* W1 = (const float*)d_in[2];
    const float* b1 = (const float*)d_in[3];
    const float* W2 = (const float*)d_in[4];
    const float* b2 = (const float*)d_in[5];
    float* out = (float*)d_out;

    const int* src = ei;             // edge_index[0]
    const int* dst = ei + N_EDGES;   // edge_index[1]

    char* ws = (char*)d_ws;
    size_t off = 0;
    int* bcursor = (int*)(ws + off);     off = align16(off + 4u * NB);
    int2* row_info = (int2*)(ws + off);  off = align16(off + 8u * (size_t)N_NODES);   // 0.8 MB
    float* dis = (float*)(ws + off);     off = align16(off + 4u * N_NODES);           // 0.4 MB
    int* csr = (int*)(ws + off);         off = align16(off + 4u * (size_t)NB * CAP);  // 8.0 MB
    unsigned* ppair = (unsigned*)(ws + off);
    off = align16(off + 4u * (size_t)NB * CAP);                                       // 8.0 MB
    unsigned short* hxs = (unsigned short*)(ws + off);
    off = align16(off + 2u * (size_t)N_NODES * HID);                                  // 12.8 MB
    unsigned short* h2s = (unsigned short*)(ws + off);
    off = align16(off + 2u * (size_t)N_NODES * NC);                                   // 2.0 MB

    k_init<<<(NB + 255) / 256, 256, 0, stream>>>(bcursor);
    s3_part<<<PBLK, 256, 0, stream>>>(src, dst, bcursor, ppair);
    s4_build<<<NB, 256, 0, stream>>>(ppair, bcursor, row_info, dis, csr);
    k_xw<<<(N_NODES + XROWS - 1) / XROWS, 256, 0, stream>>>(x, W1, dis, hxs);
    k_agg1f<<<(N_NODES * 64 + 255) / 256, 256, 0, stream>>>(
        row_info, dis, (const unsigned*)hxs, csr, b1, W2, h2s);
    k_agg2f<<<(N_NODES * 16 + 255) / 256, 256, 0, stream>>>(
        row_info, dis, h2s, csr, b2, out);
}

// Round 15
// 172.901 us; speedup vs baseline: 1.1550x; 1.1550x over previous
//
#include <hip/hip_runtime.h>
#include <hip/hip_bf16.h>

#define N_NODES 100000
#define N_EDGES 1600000
#define F_IN 128
#define HID 64
#define NC 10

#define BSH 7
#define BNODES 128                       // nodes per bucket = 1<<BSH
#define NB 782                           // ceil(100000/128)
#define CAP 2560                         // padded bucket capacity (λ=2048, +11σ)
#define PBLK 256                         // partition blocks
#define TILE ((N_EDGES + PBLK - 1) / PBLK)  // 6250 edges per block

#define XROWS 64
#define XPAD 132                         // 528 B row: 16B-aligned, 2-way banks (free)

__device__ __forceinline__ unsigned short f2bf(float f) {
    unsigned u = __float_as_uint(f);
    u += 0x7FFFu + ((u >> 16) & 1u);     // round-to-nearest-even
    return (unsigned short)(u >> 16);
}
__device__ __forceinline__ float bf2f(unsigned short b) {
    return __uint_as_float(((unsigned)b) << 16);
}

// ---------------- s3: partition edges into padded bucket regions
// bcursor zeroed by memset; reservation = k*CAP + atomicAdd(count).
// ppair entry = src | (local_dst << 20)
__global__ __launch_bounds__(256) void s3_part(const int* __restrict__ src,
                                               const int* __restrict__ dst,
                                               int* __restrict__ bcursor,
                                               unsigned* __restrict__ ppair) {
    __shared__ int lh[NB];     // histogram, then running cursor
    int t = threadIdx.x;
    for (int k = t; k < NB; k += 256) lh[k] = 0;
    __syncthreads();
    int b0 = blockIdx.x * TILE;
    int b1 = b0 + TILE < N_EDGES ? b0 + TILE : N_EDGES;
    for (int i = b0 + t; i < b1; i += 256)
        atomicAdd(&lh[dst[i] >> BSH], 1);
    __syncthreads();
    for (int k = t; k < NB; k += 256) {
        int c = lh[k];
        lh[k] = c ? (k * CAP + atomicAdd(&bcursor[k], c)) : 0;  // coalesced
    }
    __syncthreads();
    for (int i = b0 + t; i < b1; i += 256) {
        int d = dst[i];
        int slot = atomicAdd(&lh[d >> BSH], 1);      // LDS atomic (fast)
        ppair[slot] = (unsigned)src[i] | ((unsigned)(d & (BNODES - 1)) << 20);
    }
}

// ---------------- s4: per-bucket CSR finalize (row_info, dis, padded csr)
__global__ __launch_bounds__(256) void s4_build(const unsigned* __restrict__ ppair,
                                                const int* __restrict__ bcursor,
                                                int2* __restrict__ row_info,
                                                float* __restrict__ dis,
                                                int* __restrict__ csr) {
    __shared__ int h[BNODES];
    __shared__ int sc[BNODES];
    __shared__ int lcur[BNODES];
    int t = threadIdx.x;
    int b = blockIdx.x;
    int base = b * CAP;
    int cnt = bcursor[b];                // pure count (cursor started at 0)
    int nodes0 = b << BSH;
    if (t < BNODES) h[t] = 0;
    __syncthreads();
    for (int j = t; j < cnt; j += 256)
        atomicAdd(&h[ppair[base + j] >> 20], 1);
    __syncthreads();
    if (t < BNODES) sc[t] = h[t];
    __syncthreads();
    for (int off = 1; off < BNODES; off <<= 1) {
        int u = (t < BNODES && t >= off) ? sc[t - off] : 0;
        __syncthreads();
        if (t < BNODES) sc[t] += u;
        __syncthreads();
    }
    if (t < BNODES) {
        int node = nodes0 + t;
        int excl = sc[t] - h[t];
        if (node < N_NODES) {
            row_info[node] = make_int2(base + excl, h[t]);
            dis[node] = rsqrtf((float)(h[t] + 1));
            lcur[t] = base + excl;
        }
    }
    __syncthreads();
    for (int j = t; j < cnt; j += 256) {
        unsigned p = ppair[base + j];
        int slot = atomicAdd(&lcur[p >> 20], 1);        // LDS atomic
        csr[slot] = (int)(p & 0xFFFFFu);
    }
}

__device__ __forceinline__ float4 fma4(float s, float4 w, float4 a) {
    a.x = fmaf(s, w.x, a.x);
    a.y = fmaf(s, w.y, a.y);
    a.z = fmaf(s, w.z, a.z);
    a.w = fmaf(s, w.w, a.w);
    return a;
}

// ---------------- hxs = bf16((x @ W1) * dis) ; 64x64 LDS-tiled, 4x4 per thread
__global__ __launch_bounds__(256) void k_xw(const float* __restrict__ x,
                                            const float* __restrict__ W1,
                                            const float* __restrict__ dis,
                                            unsigned short* __restrict__ hxs) {
    __shared__ float Ws[F_IN * HID];      // 32 KB, [k][c] (== W1 layout)
    __shared__ float Xs[XROWS * XPAD];    // 33 KB, [n][k] padded
    int t = threadIdx.x;
    int base = blockIdx.x * XROWS;

    for (int i = t; i < (F_IN * HID) / 4; i += 256)
        reinterpret_cast<float4*>(Ws)[i] = reinterpret_cast<const float4*>(W1)[i];

    for (int i = t; i < XROWS * (F_IN / 4); i += 256) {
        int n = i >> 5;           // 32 float4 per row
        int kq = i & 31;
        int gn = base + n;
        float4 v = make_float4(0.f, 0.f, 0.f, 0.f);
        if (gn < N_NODES)
            v = reinterpret_cast<const float4*>(x + (size_t)gn * F_IN)[kq];
        *reinterpret_cast<float4*>(&Xs[n * XPAD + kq * 4]) = v;
    }
    __syncthreads();

    int cg = (t & 15) * 4;        // col base: 16 groups x 4 cols
    int ng = (t >> 4) * 4;        // node base: 16 groups x 4 nodes
    float4 a0 = make_float4(0.f, 0.f, 0.f, 0.f);
    float4 a1 = a0, a2 = a0, a3 = a0;

#pragma unroll 4
    for (int k0 = 0; k0 < F_IN; k0 += 4) {
        float4 w0 = *reinterpret_cast<const float4*>(&Ws[(k0 + 0) * HID + cg]);
        float4 w1 = *reinterpret_cast<const float4*>(&Ws[(k0 + 1) * HID + cg]);
        float4 w2 = *reinterpret_cast<const float4*>(&Ws[(k0 + 2) * HID + cg]);
        float4 w3 = *reinterpret_cast<const float4*>(&Ws[(k0 + 3) * HID + cg]);
        float4 x0 = *reinterpret_cast<const float4*>(&Xs[(ng + 0) * XPAD + k0]);
        float4 x1 = *reinterpret_cast<const float4*>(&Xs[(ng + 1) * XPAD + k0]);
        float4 x2 = *reinterpret_cast<const float4*>(&Xs[(ng + 2) * XPAD + k0]);
        float4 x3 = *reinterpret_cast<const float4*>(&Xs[(ng + 3) * XPAD + k0]);
        a0 = fma4(x0.x, w0, a0); a0 = fma4(x0.y, w1, a0);
        a0 = fma4(x0.z, w2, a0); a0 = fma4(x0.w, w3, a0);
        a1 = fma4(x1.x, w0, a1); a1 = fma4(x1.y, w1, a1);
        a1 = fma4(x1.z, w2, a1); a1 = fma4(x1.w, w3, a1);
        a2 = fma4(x2.x, w0, a2); a2 = fma4(x2.y, w1, a2);
        a2 = fma4(x2.z, w2, a2); a2 = fma4(x2.w, w3, a2);
        a3 = fma4(x3.x, w0, a3); a3 = fma4(x3.y, w1, a3);
        a3 = fma4(x3.z, w2, a3); a3 = fma4(x3.w, w3, a3);
    }

    int n0 = base + ng;
    if (n0 + 0 < N_NODES) {
        float d = dis[n0 + 0];
        ushort4 o; o.x = f2bf(a0.x * d); o.y = f2bf(a0.y * d);
        o.z = f2bf(a0.z * d); o.w = f2bf(a0.w * d);
        *reinterpret_cast<ushort4*>(&hxs[(size_t)(n0 + 0) * HID + cg]) = o;
    }
    if (n0 + 1 < N_NODES) {
        float d = dis[n0 + 1];
        ushort4 o; o.x = f2bf(a1.x * d); o.y = f2bf(a1.y * d);
        o.z = f2bf(a1.z * d); o.w = f2bf(a1.w * d);
        *reinterpret_cast<ushort4*>(&hxs[(size_t)(n0 + 1) * HID + cg]) = o;
    }
    if (n0 + 2 < N_NODES) {
        float d = dis[n0 + 2];
        ushort4 o; o.x = f2bf(a2.x * d); o.y = f2bf(a2.y * d);
        o.z = f2bf(a2.z * d); o.w = f2bf(a2.w * d);
        *reinterpret_cast<ushort4*>(&hxs[(size_t)(n0 + 2) * HID + cg]) = o;
    }
    if (n0 + 3 < N_NODES) {
        float d = dis[n0 + 3];
        ushort4 o; o.x = f2bf(a3.x * d); o.y = f2bf(a3.y * d);
        o.z = f2bf(a3.z * d); o.w = f2bf(a3.w * d);
        *reinterpret_cast<ushort4*>(&hxs[(size_t)(n0 + 3) * HID + cg]) = o;
    }
}

// ---------------- fused layer-1 aggregate + bias + relu + W2 + scale -> bf16 h2s
// One wave per node; lane&31 = uint col-pair; lane>>5 = edge parity.
// Main loop: 16 edges/iter; tail: 2 predicated 8-edge rounds. (R12 structure)
__global__ __launch_bounds__(256) void k_agg1f(const int2* __restrict__ row_info,
                                               const float* __restrict__ dis,
                                               const unsigned* __restrict__ hxsu,
                                               const int* __restrict__ csr,
                                               const float* __restrict__ b1,
                                               const float* __restrict__ W2,
                                               unsigned short* __restrict__ h2s) {
    int lane = threadIdx.x & 63;
    int node = (blockIdx.x * blockDim.x + threadIdx.x) >> 6;
    if (node >= N_NODES) return;
    int col2 = lane & 31;
    int half = lane >> 5;

    // hoisted per-lane constants (L1-cached, issued early, hidden under gather)
    float bl0 = b1[2 * col2], bl1 = b1[2 * col2 + 1];
    const float* w0p = W2 + (2 * col2) * NC;
    const float* w1p = W2 + (2 * col2 + 1) * NC;

    int2 ri = row_info[node];
    int beg = ri.x, m = ri.y;
    float ax = 0.f, ay = 0.f;
    int mmain = m & ~15;
    int j = 0;
    for (; j < mmain; j += 16) {                  // 16 edges per iter, 8 per half
        int i0 = beg + j + half;
        int e0 = csr[i0],      e1 = csr[i0 + 2];
        int e2 = csr[i0 + 4],  e3 = csr[i0 + 6];
        int e4 = csr[i0 + 8],  e5 = csr[i0 + 10];
        int e6 = csr[i0 + 12], e7 = csr[i0 + 14];
        unsigned u0 = hxsu[(size_t)e0 * 32 + col2];
        unsigned u1 = hxsu[(size_t)e1 * 32 + col2];
        unsigned u2 = hxsu[(size_t)e2 * 32 + col2];
        unsigned u3 = hxsu[(size_t)e3 * 32 + col2];
        unsigned u4 = hxsu[(size_t)e4 * 32 + col2];
        unsigned u5 = hxsu[(size_t)e5 * 32 + col2];
        unsigned u6 = hxsu[(size_t)e6 * 32 + col2];
        unsigned u7 = hxsu[(size_t)e7 * 32 + col2];
        ax += __uint_as_float(u0 << 16); ay += __uint_as_float(u0 & 0xffff0000u);
        ax += __uint_as_float(u1 << 16); ay += __uint_as_float(u1 & 0xffff0000u);
        ax += __uint_as_float(u2 << 16); ay += __uint_as_float(u2 & 0xffff0000u);
        ax += __uint_as_float(u3 << 16); ay += __uint_as_float(u3 & 0xffff0000u);
        ax += __uint_as_float(u4 << 16); ay += __uint_as_float(u4 & 0xffff0000u);
        ax += __uint_as_float(u5 << 16); ay += __uint_as_float(u5 & 0xffff0000u);
        ax += __uint_as_float(u6 << 16); ay += __uint_as_float(u6 & 0xffff0000u);
        ax += __uint_as_float(u7 << 16); ay += __uint_as_float(u7 & 0xffff0000u);
    }
#pragma unroll 2
    for (int r = 0; r < 2; ++r) {
        if (j < m) {                              // predicated 8-edge round
            int i0 = j + half;
            bool v0 = i0 < m, v1 = i0 + 2 < m, v2 = i0 + 4 < m, v3 = i0 + 6 < m;
            int e0 = csr[beg + (v0 ? i0     : 0)];
            int e1 = csr[beg + (v1 ? i0 + 2 : 0)];
            int e2 = csr[beg + (v2 ? i0 + 4 : 0)];
            int e3 = csr[beg + (v3 ? i0 + 6 : 0)];
            unsigned u0 = hxsu[(size_t)e0 * 32 + col2];
            unsigned u1 = hxsu[(size_t)e1 * 32 + col2];
            unsigned u2 = hxsu[(size_t)e2 * 32 + col2];
            unsigned u3 = hxsu[(size_t)e3 * 32 + col2];
            ax += v0 ? __uint_as_float(u0 << 16) : 0.f;
            ay += v0 ? __uint_as_float(u0 & 0xffff0000u) : 0.f;
            ax += v1 ? __uint_as_float(u1 << 16) : 0.f;
            ay += v1 ? __uint_as_float(u1 & 0xffff0000u) : 0.f;
            ax += v2 ? __uint_as_float(u2 << 16) : 0.f;
            ay += v2 ? __uint_as_float(u2 & 0xffff0000u) : 0.f;
            ax += v3 ? __uint_as_float(u3 << 16) : 0.f;
            ay += v3 ? __uint_as_float(u3 & 0xffff0000u) : 0.f;
        }
        j += 8;
    }
    ax += __shfl_xor(ax, 32);
    ay += __shfl_xor(ay, 32);
    unsigned us = hxsu[(size_t)node * 32 + col2];
    ax += __uint_as_float(us << 16);
    ay += __uint_as_float(us & 0xffff0000u);

    float dn = dis[node];
    float vx = ax * dn + bl0; vx = vx > 0.f ? vx : 0.f;
    float vy = ay * dn + bl1; vy = vy > 0.f ? vy : 0.f;

    float s0 = vx * w0p[0] + vy * w1p[0];
    float s1 = vx * w0p[1] + vy * w1p[1];
    float s2 = vx * w0p[2] + vy * w1p[2];
    float s3 = vx * w0p[3] + vy * w1p[3];
    float s4 = vx * w0p[4] + vy * w1p[4];
    float s5 = vx * w0p[5] + vy * w1p[5];
    float s6 = vx * w0p[6] + vy * w1p[6];
    float s7 = vx * w0p[7] + vy * w1p[7];
    float s8 = vx * w0p[8] + vy * w1p[8];
    float s9 = vx * w0p[9] + vy * w1p[9];
#pragma unroll
    for (int off = 16; off >= 1; off >>= 1) {     // 5 rounds over 32-lane halves
        s0 += __shfl_xor(s0, off); s1 += __shfl_xor(s1, off);
        s2 += __shfl_xor(s2, off); s3 += __shfl_xor(s3, off);
        s4 += __shfl_xor(s4, off); s5 += __shfl_xor(s5, off);
        s6 += __shfl_xor(s6, off); s7 += __shfl_xor(s7, off);
        s8 += __shfl_xor(s8, off); s9 += __shfl_xor(s9, off);
    }
    float o = s0;
    o = (lane == 1) ? s1 : o; o = (lane == 2) ? s2 : o;
    o = (lane == 3) ? s3 : o; o = (lane == 4) ? s4 : o;
    o = (lane == 5) ? s5 : o; o = (lane == 6) ? s6 : o;
    o = (lane == 7) ? s7 : o; o = (lane == 8) ? s8 : o;
    o = (lane == 9) ? s9 : o;
    if (lane < NC)
        h2s[(size_t)node * NC + lane] = f2bf(o * dn);
}

// ---------------- layer-2 aggregate + bias + log_softmax (bf16 h2s)
// 16 lanes per node; 4 edges per iter + predicated 4-edge tail. (R12 version)
__global__ __launch_bounds__(256) void k_agg2f(const int2* __restrict__ row_info,
                                               const float* __restrict__ dis,
                                               const unsigned short* __restrict__ h2s,
                                               const int* __restrict__ csr,
                                               const float* __restrict__ b2,
                                               float* __restrict__ out) {
    int c = threadIdx.x & 15;  // 16 lanes per node, 10 active
    int node = (blockIdx.x * blockDim.x + threadIdx.x) >> 4;
    if (node >= N_NODES) return;
    int cc = c < NC ? c : 0;
    int2 ri = row_info[node];
    int beg = ri.x, m = ri.y;
    float acc = bf2f(h2s[(size_t)node * NC + cc]);
    int mmain = m & ~3;
    int j = 0;
    for (; j < mmain; j += 4) {                   // 4 independent loads in flight
        int e0 = csr[beg + j],     e1 = csr[beg + j + 1];
        int e2 = csr[beg + j + 2], e3 = csr[beg + j + 3];
        float f0 = bf2f(h2s[(size_t)e0 * NC + cc]);
        float f1 = bf2f(h2s[(size_t)e1 * NC + cc]);
        float f2 = bf2f(h2s[(size_t)e2 * NC + cc]);
        float f3 = bf2f(h2s[(size_t)e3 * NC + cc]);
        acc += f0 + f1 + f2 + f3;
    }
    if (j < m) {                                  // predicated 4-edge tail
        bool v0 = j < m, v1 = j + 1 < m, v2 = j + 2 < m, v3 = j + 3 < m;
        int e0 = csr[beg + (v0 ? j     : 0)];
        int e1 = csr[beg + (v1 ? j + 1 : 0)];
        int e2 = csr[beg + (v2 ? j + 2 : 0)];
        int e3 = csr[beg + (v3 ? j + 3 : 0)];
        float f0 = bf2f(h2s[(size_t)e0 * NC + cc]);
        float f1 = bf2f(h2s[(size_t)e1 * NC + cc]);
        float f2 = bf2f(h2s[(size_t)e2 * NC + cc]);
        float f3 = bf2f(h2s[(size_t)e3 * NC + cc]);
        acc += v0 ? f0 : 0.f;
        acc += v1 ? f1 : 0.f;
        acc += v2 ? f2 : 0.f;
        acc += v3 ? f3 : 0.f;
    }
    acc = acc * dis[node] + b2[cc];
    float accm = (c < NC) ? acc : -1e30f;
    float mx = accm;
#pragma unroll
    for (int off = 8; off >= 1; off >>= 1)
        mx = fmaxf(mx, __shfl_xor(mx, off, 16));
    float e = (c < NC) ? expf(acc - mx) : 0.f;
    float ssum = e;
#pragma unroll
    for (int off = 8; off >= 1; off >>= 1)
        ssum += __shfl_xor(ssum, off, 16);
    float lse = mx + logf(ssum);
    if (c < NC) out[(size_t)node * NC + c] = acc - lse;
}

static inline size_t align16(size_t v) { return (v + 15) & ~(size_t)15; }

extern "C" void kernel_launch(void* const* d_in, const int* in_sizes, int n_in,
                              void* d_out, int out_size, void* d_ws, size_t ws_size,
                              hipStream_t stream) {
    const float* x  = (const float*)d_in[0];
    const int*   ei = (const int*)d_in[1];    // [2, E] int32 (JAX x64 off)
    const float* W1 = (const float*)d_in[2];
    const float* b1 = (const float*)d_in[3];
    const float* W2 = (const float*)d_in[4];
    const float* b2 = (const float*)d_in[5];
    float* out = (float*)d_out;

    const int* src = ei;             // edge_index[0]
    const int* dst = ei + N_EDGES;   // edge_index[1]

    char* ws = (char*)d_ws;
    size_t off = 0;
    int* bcursor = (int*)(ws + off);     off = align16(off + 4u * NB);
    int2* row_info = (int2*)(ws + off);  off = align16(off + 8u * (size_t)N_NODES);   // 0.8 MB
    float* dis = (float*)(ws + off);     off = align16(off + 4u * N_NODES);           // 0.4 MB
    int* csr = (int*)(ws + off);         off = align16(off + 4u * (size_t)NB * CAP);  // 8.0 MB
    unsigned* ppair = (unsigned*)(ws + off);
    off = align16(off + 4u * (size_t)NB * CAP);                                       // 8.0 MB
    unsigned short* hxs = (unsigned short*)(ws + off);
    off = align16(off + 2u * (size_t)N_NODES * HID);                                  // 12.8 MB
    unsigned short* h2s = (unsigned short*)(ws + off);
    off = align16(off + 2u * (size_t)N_NODES * NC);                                   // 2.0 MB

    hipMemsetAsync(bcursor, 0, 4u * NB, stream);
    s3_part<<<PBLK, 256, 0, stream>>>(src, dst, bcursor, ppair);
    s4_build<<<NB, 256, 0, stream>>>(ppair, bcursor, row_info, dis, csr);
    k_xw<<<(N_NODES + XROWS - 1) / XROWS, 256, 0, stream>>>(x, W1, dis, hxs);
    k_agg1f<<<(N_NODES * 64 + 255) / 256, 256, 0, stream>>>(
        row_info, dis, (const unsigned*)hxs, csr, b1, W2, h2s);
    k_agg2f<<<(N_NODES * 16 + 255) / 256, 256, 0, stream>>>(
        row_info, dis, h2s, csr, b2, out);
}

// Round 16
// 170.445 us; speedup vs baseline: 1.1716x; 1.0144x over previous
//
#include <hip/hip_runtime.h>
#include <hip/hip_bf16.h>

#define N_NODES 100000
#define N_EDGES 1600000
#define F_IN 128
#define HID 64
#define NC 10

#define BSH 7
#define BNODES 128                       // nodes per bucket = 1<<BSH
#define NB 782                           // ceil(100000/128)
#define CAP 2560                         // padded bucket capacity (λ=2048, +11σ)
#define PBLK 512                         // partition blocks (2 blocks/CU)
#define PTHR 512                         // partition threads per block
#define TILE ((N_EDGES + PBLK - 1) / PBLK)  // 3125 edges per block (exact)

#define XROWS 64
#define XPAD 132                         // 528 B row: 16B-aligned, 2-way banks (free)

__device__ __forceinline__ unsigned short f2bf(float f) {
    unsigned u = __float_as_uint(f);
    u += 0x7FFFu + ((u >> 16) & 1u);     // round-to-nearest-even
    return (unsigned short)(u >> 16);
}
__device__ __forceinline__ float bf2f(unsigned short b) {
    return __uint_as_float(((unsigned)b) << 16);
}

// ---------------- s3: partition edges into padded bucket regions
// 512 threads x 512 blocks (16 waves/CU). bcursor zeroed by memset;
// reservation = k*CAP + atomicAdd(count). ppair = src | (local_dst << 20)
__global__ __launch_bounds__(PTHR) void s3_part(const int* __restrict__ src,
                                                const int* __restrict__ dst,
                                                int* __restrict__ bcursor,
                                                unsigned* __restrict__ ppair) {
    __shared__ int lh[NB];     // histogram, then running cursor
    int t = threadIdx.x;
    for (int k = t; k < NB; k += PTHR) lh[k] = 0;
    __syncthreads();
    int b0 = blockIdx.x * TILE;
    int b1 = b0 + TILE < N_EDGES ? b0 + TILE : N_EDGES;
    for (int i = b0 + t; i < b1; i += PTHR)
        atomicAdd(&lh[dst[i] >> BSH], 1);
    __syncthreads();
    for (int k = t; k < NB; k += PTHR) {
        int c = lh[k];
        lh[k] = c ? (k * CAP + atomicAdd(&bcursor[k], c)) : 0;  // coalesced
    }
    __syncthreads();
    for (int i = b0 + t; i < b1; i += PTHR) {
        int d = dst[i];
        int slot = atomicAdd(&lh[d >> BSH], 1);      // LDS atomic (fast)
        ppair[slot] = (unsigned)src[i] | ((unsigned)(d & (BNODES - 1)) << 20);
    }
}

// ---------------- s4: per-bucket CSR finalize (row_info, dis, padded csr)
__global__ __launch_bounds__(256) void s4_build(const unsigned* __restrict__ ppair,
                                                const int* __restrict__ bcursor,
                                                int2* __restrict__ row_info,
                                                float* __restrict__ dis,
                                                int* __restrict__ csr) {
    __shared__ int h[BNODES];
    __shared__ int sc[BNODES];
    __shared__ int lcur[BNODES];
    int t = threadIdx.x;
    int b = blockIdx.x;
    int base = b * CAP;
    int cnt = bcursor[b];                // pure count (cursor started at 0)
    int nodes0 = b << BSH;
    if (t < BNODES) h[t] = 0;
    __syncthreads();
    for (int j = t; j < cnt; j += 256)
        atomicAdd(&h[ppair[base + j] >> 20], 1);
    __syncthreads();
    if (t < BNODES) sc[t] = h[t];
    __syncthreads();
    for (int off = 1; off < BNODES; off <<= 1) {
        int u = (t < BNODES && t >= off) ? sc[t - off] : 0;
        __syncthreads();
        if (t < BNODES) sc[t] += u;
        __syncthreads();
    }
    if (t < BNODES) {
        int node = nodes0 + t;
        int excl = sc[t] - h[t];
        if (node < N_NODES) {
            row_info[node] = make_int2(base + excl, h[t]);
            dis[node] = rsqrtf((float)(h[t] + 1));
            lcur[t] = base + excl;
        }
    }
    __syncthreads();
    for (int j = t; j < cnt; j += 256) {
        unsigned p = ppair[base + j];
        int slot = atomicAdd(&lcur[p >> 20], 1);        // LDS atomic
        csr[slot] = (int)(p & 0xFFFFFu);
    }
}

__device__ __forceinline__ float4 fma4(float s, float4 w, float4 a) {
    a.x = fmaf(s, w.x, a.x);
    a.y = fmaf(s, w.y, a.y);
    a.z = fmaf(s, w.z, a.z);
    a.w = fmaf(s, w.w, a.w);
    return a;
}

// ---------------- hxs = bf16((x @ W1) * dis) ; 64x64 LDS-tiled, 4x4 per thread
__global__ __launch_bounds__(256) void k_xw(const float* __restrict__ x,
                                            const float* __restrict__ W1,
                                            const float* __restrict__ dis,
                                            unsigned short* __restrict__ hxs) {
    __shared__ float Ws[F_IN * HID];      // 32 KB, [k][c] (== W1 layout)
    __shared__ float Xs[XROWS * XPAD];    // 33 KB, [n][k] padded
    int t = threadIdx.x;
    int base = blockIdx.x * XROWS;

    for (int i = t; i < (F_IN * HID) / 4; i += 256)
        reinterpret_cast<float4*>(Ws)[i] = reinterpret_cast<const float4*>(W1)[i];

    for (int i = t; i < XROWS * (F_IN / 4); i += 256) {
        int n = i >> 5;           // 32 float4 per row
        int kq = i & 31;
        int gn = base + n;
        float4 v = make_float4(0.f, 0.f, 0.f, 0.f);
        if (gn < N_NODES)
            v = reinterpret_cast<const float4*>(x + (size_t)gn * F_IN)[kq];
        *reinterpret_cast<float4*>(&Xs[n * XPAD + kq * 4]) = v;
    }
    __syncthreads();

    int cg = (t & 15) * 4;        // col base: 16 groups x 4 cols
    int ng = (t >> 4) * 4;        // node base: 16 groups x 4 nodes
    float4 a0 = make_float4(0.f, 0.f, 0.f, 0.f);
    float4 a1 = a0, a2 = a0, a3 = a0;

#pragma unroll 4
    for (int k0 = 0; k0 < F_IN; k0 += 4) {
        float4 w0 = *reinterpret_cast<const float4*>(&Ws[(k0 + 0) * HID + cg]);
        float4 w1 = *reinterpret_cast<const float4*>(&Ws[(k0 + 1) * HID + cg]);
        float4 w2 = *reinterpret_cast<const float4*>(&Ws[(k0 + 2) * HID + cg]);
        float4 w3 = *reinterpret_cast<const float4*>(&Ws[(k0 + 3) * HID + cg]);
        float4 x0 = *reinterpret_cast<const float4*>(&Xs[(ng + 0) * XPAD + k0]);
        float4 x1 = *reinterpret_cast<const float4*>(&Xs[(ng + 1) * XPAD + k0]);
        float4 x2 = *reinterpret_cast<const float4*>(&Xs[(ng + 2) * XPAD + k0]);
        float4 x3 = *reinterpret_cast<const float4*>(&Xs[(ng + 3) * XPAD + k0]);
        a0 = fma4(x0.x, w0, a0); a0 = fma4(x0.y, w1, a0);
        a0 = fma4(x0.z, w2, a0); a0 = fma4(x0.w, w3, a0);
        a1 = fma4(x1.x, w0, a1); a1 = fma4(x1.y, w1, a1);
        a1 = fma4(x1.z, w2, a1); a1 = fma4(x1.w, w3, a1);
        a2 = fma4(x2.x, w0, a2); a2 = fma4(x2.y, w1, a2);
        a2 = fma4(x2.z, w2, a2); a2 = fma4(x2.w, w3, a2);
        a3 = fma4(x3.x, w0, a3); a3 = fma4(x3.y, w1, a3);
        a3 = fma4(x3.z, w2, a3); a3 = fma4(x3.w, w3, a3);
    }

    int n0 = base + ng;
    if (n0 + 0 < N_NODES) {
        float d = dis[n0 + 0];
        ushort4 o; o.x = f2bf(a0.x * d); o.y = f2bf(a0.y * d);
        o.z = f2bf(a0.z * d); o.w = f2bf(a0.w * d);
        *reinterpret_cast<ushort4*>(&hxs[(size_t)(n0 + 0) * HID + cg]) = o;
    }
    if (n0 + 1 < N_NODES) {
        float d = dis[n0 + 1];
        ushort4 o; o.x = f2bf(a1.x * d); o.y = f2bf(a1.y * d);
        o.z = f2bf(a1.z * d); o.w = f2bf(a1.w * d);
        *reinterpret_cast<ushort4*>(&hxs[(size_t)(n0 + 1) * HID + cg]) = o;
    }
    if (n0 + 2 < N_NODES) {
        float d = dis[n0 + 2];
        ushort4 o; o.x = f2bf(a2.x * d); o.y = f2bf(a2.y * d);
        o.z = f2bf(a2.z * d); o.w = f2bf(a2.w * d);
        *reinterpret_cast<ushort4*>(&hxs[(size_t)(n0 + 2) * HID + cg]) = o;
    }
    if (n0 + 3 < N_NODES) {
        float d = dis[n0 + 3];
        ushort4 o; o.x = f2bf(a3.x * d); o.y = f2bf(a3.y * d);
        o.z = f2bf(a3.z * d); o.w = f2bf(a3.w * d);
        *reinterpret_cast<ushort4*>(&hxs[(size_t)(n0 + 3) * HID + cg]) = o;
    }
}

// ---------------- fused layer-1 aggregate + bias + relu + W2 + scale -> bf16 h2s
// One wave per node; lane&31 = uint col-pair; lane>>5 = edge parity.
// Main loop: 16 edges/iter; tail: 2 predicated 8-edge rounds. (R12 structure)
__global__ __launch_bounds__(256) void k_agg1f(const int2* __restrict__ row_info,
                                               const float* __restrict__ dis,
                                               const unsigned* __restrict__ hxsu,
                                               const int* __restrict__ csr,
                                               const float* __restrict__ b1,
                                               const float* __restrict__ W2,
                                               unsigned short* __restrict__ h2s) {
    int lane = threadIdx.x & 63;
    int node = (blockIdx.x * blockDim.x + threadIdx.x) >> 6;
    if (node >= N_NODES) return;
    int col2 = lane & 31;
    int half = lane >> 5;

    // hoisted per-lane constants (L1-cached, issued early, hidden under gather)
    float bl0 = b1[2 * col2], bl1 = b1[2 * col2 + 1];
    const float* w0p = W2 + (2 * col2) * NC;
    const float* w1p = W2 + (2 * col2 + 1) * NC;

    int2 ri = row_info[node];
    int beg = ri.x, m = ri.y;
    float ax = 0.f, ay = 0.f;
    int mmain = m & ~15;
    int j = 0;
    for (; j < mmain; j += 16) {                  // 16 edges per iter, 8 per half
        int i0 = beg + j + half;
        int e0 = csr[i0],      e1 = csr[i0 + 2];
        int e2 = csr[i0 + 4],  e3 = csr[i0 + 6];
        int e4 = csr[i0 + 8],  e5 = csr[i0 + 10];
        int e6 = csr[i0 + 12], e7 = csr[i0 + 14];
        unsigned u0 = hxsu[(size_t)e0 * 32 + col2];
        unsigned u1 = hxsu[(size_t)e1 * 32 + col2];
        unsigned u2 = hxsu[(size_t)e2 * 32 + col2];
        unsigned u3 = hxsu[(size_t)e3 * 32 + col2];
        unsigned u4 = hxsu[(size_t)e4 * 32 + col2];
        unsigned u5 = hxsu[(size_t)e5 * 32 + col2];
        unsigned u6 = hxsu[(size_t)e6 * 32 + col2];
        unsigned u7 = hxsu[(size_t)e7 * 32 + col2];
        ax += __uint_as_float(u0 << 16); ay += __uint_as_float(u0 & 0xffff0000u);
        ax += __uint_as_float(u1 << 16); ay += __uint_as_float(u1 & 0xffff0000u);
        ax += __uint_as_float(u2 << 16); ay += __uint_as_float(u2 & 0xffff0000u);
        ax += __uint_as_float(u3 << 16); ay += __uint_as_float(u3 & 0xffff0000u);
        ax += __uint_as_float(u4 << 16); ay += __uint_as_float(u4 & 0xffff0000u);
        ax += __uint_as_float(u5 << 16); ay += __uint_as_float(u5 & 0xffff0000u);
        ax += __uint_as_float(u6 << 16); ay += __uint_as_float(u6 & 0xffff0000u);
        ax += __uint_as_float(u7 << 16); ay += __uint_as_float(u7 & 0xffff0000u);
    }
#pragma unroll 2
    for (int r = 0; r < 2; ++r) {
        if (j < m) {                              // predicated 8-edge round
            int i0 = j + half;
            bool v0 = i0 < m, v1 = i0 + 2 < m, v2 = i0 + 4 < m, v3 = i0 + 6 < m;
            int e0 = csr[beg + (v0 ? i0     : 0)];
            int e1 = csr[beg + (v1 ? i0 + 2 : 0)];
            int e2 = csr[beg + (v2 ? i0 + 4 : 0)];
            int e3 = csr[beg + (v3 ? i0 + 6 : 0)];
            unsigned u0 = hxsu[(size_t)e0 * 32 + col2];
            unsigned u1 = hxsu[(size_t)e1 * 32 + col2];
            unsigned u2 = hxsu[(size_t)e2 * 32 + col2];
            unsigned u3 = hxsu[(size_t)e3 * 32 + col2];
            ax += v0 ? __uint_as_float(u0 << 16) : 0.f;
            ay += v0 ? __uint_as_float(u0 & 0xffff0000u) : 0.f;
            ax += v1 ? __uint_as_float(u1 << 16) : 0.f;
            ay += v1 ? __uint_as_float(u1 & 0xffff0000u) : 0.f;
            ax += v2 ? __uint_as_float(u2 << 16) : 0.f;
            ay += v2 ? __uint_as_float(u2 & 0xffff0000u) : 0.f;
            ax += v3 ? __uint_as_float(u3 << 16) : 0.f;
            ay += v3 ? __uint_as_float(u3 & 0xffff0000u) : 0.f;
        }
        j += 8;
    }
    ax += __shfl_xor(ax, 32);
    ay += __shfl_xor(ay, 32);
    unsigned us = hxsu[(size_t)node * 32 + col2];
    ax += __uint_as_float(us << 16);
    ay += __uint_as_float(us & 0xffff0000u);

    float dn = dis[node];
    float vx = ax * dn + bl0; vx = vx > 0.f ? vx : 0.f;
    float vy = ay * dn + bl1; vy = vy > 0.f ? vy : 0.f;

    float s0 = vx * w0p[0] + vy * w1p[0];
    float s1 = vx * w0p[1] + vy * w1p[1];
    float s2 = vx * w0p[2] + vy * w1p[2];
    float s3 = vx * w0p[3] + vy * w1p[3];
    float s4 = vx * w0p[4] + vy * w1p[4];
    float s5 = vx * w0p[5] + vy * w1p[5];
    float s6 = vx * w0p[6] + vy * w1p[6];
    float s7 = vx * w0p[7] + vy * w1p[7];
    float s8 = vx * w0p[8] + vy * w1p[8];
    float s9 = vx * w0p[9] + vy * w1p[9];
#pragma unroll
    for (int off = 16; off >= 1; off >>= 1) {     // 5 rounds over 32-lane halves
        s0 += __shfl_xor(s0, off); s1 += __shfl_xor(s1, off);
        s2 += __shfl_xor(s2, off); s3 += __shfl_xor(s3, off);
        s4 += __shfl_xor(s4, off); s5 += __shfl_xor(s5, off);
        s6 += __shfl_xor(s6, off); s7 += __shfl_xor(s7, off);
        s8 += __shfl_xor(s8, off); s9 += __shfl_xor(s9, off);
    }
    float o = s0;
    o = (lane == 1) ? s1 : o; o = (lane == 2) ? s2 : o;
    o = (lane == 3) ? s3 : o; o = (lane == 4) ? s4 : o;
    o = (lane == 5) ? s5 : o; o = (lane == 6) ? s6 : o;
    o = (lane == 7) ? s7 : o; o = (lane == 8) ? s8 : o;
    o = (lane == 9) ? s9 : o;
    if (lane < NC)
        h2s[(size_t)node * NC + lane] = f2bf(o * dn);
}

// ---------------- layer-2 aggregate + bias + log_softmax (bf16 h2s)
// 16 lanes per node; 4 edges per iter + predicated 4-edge tail. (R12 version)
__global__ __launch_bounds__(256) void k_agg2f(const int2* __restrict__ row_info,
                                               const float* __restrict__ dis,
                                               const unsigned short* __restrict__ h2s,
                                               const int* __restrict__ csr,
                                               const float* __restrict__ b2,
                                               float* __restrict__ out) {
    int c = threadIdx.x & 15;  // 16 lanes per node, 10 active
    int node = (blockIdx.x * blockDim.x + threadIdx.x) >> 4;
    if (node >= N_NODES) return;
    int cc = c < NC ? c : 0;
    int2 ri = row_info[node];
    int beg = ri.x, m = ri.y;
    float acc = bf2f(h2s[(size_t)node * NC + cc]);
    int mmain = m & ~3;
    int j = 0;
    for (; j < mmain; j += 4) {                   // 4 independent loads in flight
        int e0 = csr[beg + j],     e1 = csr[beg + j + 1];
        int e2 = csr[beg + j + 2], e3 = csr[beg + j + 3];
        float f0 = bf2f(h2s[(size_t)e0 * NC + cc]);
        float f1 = bf2f(h2s[(size_t)e1 * NC + cc]);
        float f2 = bf2f(h2s[(size_t)e2 * NC + cc]);
        float f3 = bf2f(h2s[(size_t)e3 * NC + cc]);
        acc += f0 + f1 + f2 + f3;
    }
    if (j < m) {                                  // predicated 4-edge tail
        bool v0 = j < m, v1 = j + 1 < m, v2 = j + 2 < m, v3 = j + 3 < m;
        int e0 = csr[beg + (v0 ? j     : 0)];
        int e1 = csr[beg + (v1 ? j + 1 : 0)];
        int e2 = csr[beg + (v2 ? j + 2 : 0)];
        int e3 = csr[beg + (v3 ? j + 3 : 0)];
        float f0 = bf2f(h2s[(size_t)e0 * NC + cc]);
        float f1 = bf2f(h2s[(size_t)e1 * NC + cc]);
        float f2 = bf2f(h2s[(size_t)e2 * NC + cc]);
        float f3 = bf2f(h2s[(size_t)e3 * NC + cc]);
        acc += v0 ? f0 : 0.f;
        acc += v1 ? f1 : 0.f;
        acc += v2 ? f2 : 0.f;
        acc += v3 ? f3 : 0.f;
    }
    acc = acc * dis[node] + b2[cc];
    float accm = (c < NC) ? acc : -1e30f;
    float mx = accm;
#pragma unroll
    for (int off = 8; off >= 1; off >>= 1)
        mx = fmaxf(mx, __shfl_xor(mx, off, 16));
    float e = (c < NC) ? expf(acc - mx) : 0.f;
    float ssum = e;
#pragma unroll
    for (int off = 8; off >= 1; off >>= 1)
        ssum += __shfl_xor(ssum, off, 16);
    float lse = mx + logf(ssum);
    if (c < NC) out[(size_t)node * NC + c] = acc - lse;
}

static inline size_t align16(size_t v) { return (v + 15) & ~(size_t)15; }

extern "C" void kernel_launch(void* const* d_in, const int* in_sizes, int n_in,
                              void* d_out, int out_size, void* d_ws, size_t ws_size,
                              hipStream_t stream) {
    const float* x  = (const float*)d_in[0];
    const int*   ei = (const int*)d_in[1];    // [2, E] int32 (JAX x64 off)
    const float* W1 = (const float*)d_in[2];
    const float* b1 = (const float*)d_in[3];
    const float* W2 = (const float*)d_in[4];
    const float* b2 = (const float*)d_in[5];
    float* out = (float*)d_out;

    const int* src = ei;             // edge_index[0]
    const int* dst = ei + N_EDGES;   // edge_index[1]

    char* ws = (char*)d_ws;
    size_t off = 0;
    int* bcursor = (int*)(ws + off);     off = align16(off + 4u * NB);
    int2* row_info = (int2*)(ws + off);  off = align16(off + 8u * (size_t)N_NODES);   // 0.8 MB
    float* dis = (float*)(ws + off);     off = align16(off + 4u * N_NODES);           // 0.4 MB
    int* csr = (int*)(ws + off);         off = align16(off + 4u * (size_t)NB * CAP);  // 8.0 MB
    unsigned* ppair = (unsigned*)(ws + off);
    off = align16(off + 4u * (size_t)NB * CAP);                                       // 8.0 MB
    unsigned short* hxs = (unsigned short*)(ws + off);
    off = align16(off + 2u * (size_t)N_NODES * HID);                                  // 12.8 MB
    unsigned short* h2s = (unsigned short*)(ws + off);
    off = align16(off + 2u * (size_t)N_NODES * NC);                                   // 2.0 MB

    hipMemsetAsync(bcursor, 0, 4u * NB, stream);
    s3_part<<<PBLK, PTHR, 0, stream>>>(src, dst, bcursor, ppair);
    s4_build<<<NB, 256, 0, stream>>>(ppair, bcursor, row_info, dis, csr);
    k_xw<<<(N_NODES + XROWS - 1) / XROWS, 256, 0, stream>>>(x, W1, dis, hxs);
    k_agg1f<<<(N_NODES * 64 + 255) / 256, 256, 0, stream>>>(
        row_info, dis, (const unsigned*)hxs, csr, b1, W2, h2s);
    k_agg2f<<<(N_NODES * 16 + 255) / 256, 256, 0, stream>>>(
        row_info, dis, h2s, csr, b2, out);
}